// Round 1
// baseline (3259.752 us; speedup 1.0000x reference)
//
#include <hip/hip_runtime.h>
#include <hip/hip_bf16.h>
#include <math.h>

#define TT 128      // time steps
#define CC 256      // channels
#define NL4 64      // float4 per channel row
#define MAXLEN 80

// One workgroup per batch element b. 256 threads = 4 waves.
// Wave w owns output rows t0..t0+31 (t0 = 32*w); lane l owns channels 4l..4l+3.
// LDS xs holds enc rows at slot t+1 (slots 0 and 129 are the zero halo);
// after conv1+LN it is overwritten with x1 at the same slot convention.
__global__ __launch_bounds__(256, 1)
void va_fused(const float* __restrict__ enc,
              const float* __restrict__ w1g, const float* __restrict__ b1g,
              const float* __restrict__ w2g, const float* __restrict__ b2g,
              const float* __restrict__ gg,  const float* __restrict__ bbg,
              const float* __restrict__ dwg, const float* __restrict__ dbg,
              float* __restrict__ outg)
{
    __shared__ float xs[130 * CC];   // 133 KB: enc then x1 (slot = t+1)
    __shared__ int   durS[TT];
    __shared__ int   cumS[TT];
    __shared__ int   wtotS[2];

    const int b    = blockIdx.x;
    const int tid  = threadIdx.x;
    const int wid  = tid >> 6;
    const int lane = tid & 63;
    const int c4   = lane << 2;   // channel base for this lane
    const int t0   = wid << 5;    // row base for this wave

    const float4* encB4 = reinterpret_cast<const float4*>(enc) + (size_t)b * (TT * NL4);
    float4* xs4 = reinterpret_cast<float4*>(xs);

    // ---- load enc into xs (slot t+1), zero halo slots 0 and 129 ----
    for (int m = tid; m < 130 * NL4; m += 256) {
        const int slot = m >> 6;
        const int t = slot - 1;
        float4 v = make_float4(0.f, 0.f, 0.f, 0.f);
        if (t >= 0 && t < TT) v = encB4[t * NL4 + (m & 63)];
        xs4[m] = v;
    }
    __syncthreads();

    float4 acc[32];   // 128 VGPRs of accumulator: rows t0..t0+31 x channels c4..c4+3

    // 16 FMAs per row for 4 consecutive K-rows (kkg..kkg+3); a-value is a
    // wave-uniform LDS broadcast, weights are per-lane registers.
    auto fma_block = [&](int kkg, const float4& w0, const float4& w1,
                         const float4& w2, const float4& w3) {
        const int k = kkg >> 8;     // conv tap 0..2
        const int c = kkg & 255;    // input channel
        const float* abase = xs + (t0 + k) * CC + c;   // slot (t-1+k)+1 = t+k
        #pragma unroll
        for (int r = 0; r < 32; ++r) {
            const float4 a = *reinterpret_cast<const float4*>(abase + r * CC);
            acc[r].x = fmaf(a.x, w0.x, acc[r].x);
            acc[r].x = fmaf(a.y, w1.x, acc[r].x);
            acc[r].x = fmaf(a.z, w2.x, acc[r].x);
            acc[r].x = fmaf(a.w, w3.x, acc[r].x);
            acc[r].y = fmaf(a.x, w0.y, acc[r].y);
            acc[r].y = fmaf(a.y, w1.y, acc[r].y);
            acc[r].y = fmaf(a.z, w2.y, acc[r].y);
            acc[r].y = fmaf(a.w, w3.y, acc[r].y);
            acc[r].z = fmaf(a.x, w0.z, acc[r].z);
            acc[r].z = fmaf(a.y, w1.z, acc[r].z);
            acc[r].z = fmaf(a.z, w2.z, acc[r].z);
            acc[r].z = fmaf(a.w, w3.z, acc[r].z);
            acc[r].w = fmaf(a.x, w0.w, acc[r].w);
            acc[r].w = fmaf(a.y, w1.w, acc[r].w);
            acc[r].w = fmaf(a.z, w2.w, acc[r].w);
            acc[r].w = fmaf(a.w, w3.w, acc[r].w);
        }
    };

    // K=768 GEMM; weights streamed from L2 (w fits per-XCD L2), 2-deep
    // register prefetch so L2 latency hides under the 512-FMA blocks.
    auto conv_gemm = [&](const float* __restrict__ wsrc, const float* __restrict__ bsrc) {
        const float4 bias = *reinterpret_cast<const float4*>(bsrc + c4);
        #pragma unroll
        for (int r = 0; r < 32; ++r) acc[r] = bias;
        const float4* w4 = reinterpret_cast<const float4*>(wsrc);
        float4 a0 = w4[0 * 64 + lane];
        float4 a1 = w4[1 * 64 + lane];
        float4 a2 = w4[2 * 64 + lane];
        float4 a3 = w4[3 * 64 + lane];
        #pragma unroll 1
        for (int it = 0; it < 192; it += 2) {
            const int base1 = (it + 1) << 2;
            float4 b0 = w4[(base1 + 0) * 64 + lane];
            float4 b1 = w4[(base1 + 1) * 64 + lane];
            float4 b2 = w4[(base1 + 2) * 64 + lane];
            float4 b3 = w4[(base1 + 3) * 64 + lane];
            fma_block(it << 2, a0, a1, a2, a3);
            if (it + 2 < 192) {
                const int base2 = (it + 2) << 2;
                a0 = w4[(base2 + 0) * 64 + lane];
                a1 = w4[(base2 + 1) * 64 + lane];
                a2 = w4[(base2 + 2) * 64 + lane];
                a3 = w4[(base2 + 3) * 64 + lane];
            }
            fma_block((it + 1) << 2, b0, b1, b2, b3);
        }
    };

    // relu then LayerNorm per row (two-pass var = mean((x-mu)^2), matches ref)
    auto relu_ln = [&]() {
        const float4 gv = *reinterpret_cast<const float4*>(gg + c4);
        const float4 bv = *reinterpret_cast<const float4*>(bbg + c4);
        #pragma unroll
        for (int r = 0; r < 32; ++r) {
            float4 v = acc[r];
            v.x = fmaxf(v.x, 0.f); v.y = fmaxf(v.y, 0.f);
            v.z = fmaxf(v.z, 0.f); v.w = fmaxf(v.w, 0.f);
            float s = (v.x + v.y) + (v.z + v.w);
            #pragma unroll
            for (int o = 32; o > 0; o >>= 1) s += __shfl_xor(s, o, 64);
            const float mu = s * (1.0f / 256.0f);
            const float dx = v.x - mu, dy = v.y - mu, dz = v.z - mu, dq = v.w - mu;
            float qq = (dx * dx + dy * dy) + (dz * dz + dq * dq);
            #pragma unroll
            for (int o = 32; o > 0; o >>= 1) qq += __shfl_xor(qq, o, 64);
            const float var = qq * (1.0f / 256.0f);
            const float rs = 1.0f / sqrtf(var + 1e-6f);
            acc[r].x = dx * rs * gv.x + bv.x;
            acc[r].y = dy * rs * gv.y + bv.y;
            acc[r].z = dz * rs * gv.z + bv.z;
            acc[r].w = dq * rs * gv.w + bv.w;
        }
    };

    // ---- conv1 + relu + LN ----
    conv_gemm(w1g, b1g);
    relu_ln();
    __syncthreads();               // all waves done reading enc from xs
    #pragma unroll
    for (int r = 0; r < 32; ++r)   // write x1 at slot t+1 (halos stay zero)
        *reinterpret_cast<float4*>(&xs[(t0 + r + 1) * CC + c4]) = acc[r];
    __syncthreads();

    // ---- conv2 + relu + LN ----
    conv_gemm(w2g, b2g);
    relu_ln();

    // ---- dense -> clip -> round(half-even) -> int durations ----
    {
        const float4 dv = *reinterpret_cast<const float4*>(dwg + c4);
        const float db0 = dbg[0];
        #pragma unroll
        for (int r = 0; r < 32; ++r) {
            const float4 v = acc[r];
            float p = (v.x * dv.x + v.y * dv.y) + (v.z * dv.z + v.w * dv.w);
            #pragma unroll
            for (int o = 32; o > 0; o >>= 1) p += __shfl_xor(p, o, 64);
            if (lane == 0) {
                const float pd  = p + db0;
                const float dcl = fminf(fmaxf(pd, 0.0f), 75.0f);
                durS[t0 + r] = (int)rintf(dcl);   // RTNE matches jnp.round
            }
        }
    }
    __syncthreads();

    // ---- inclusive cumsum over T=128 (two-wave scan) ----
    int sv = 0;
    if (tid < TT) {
        sv = durS[tid];
        #pragma unroll
        for (int o = 1; o < 64; o <<= 1) {
            const int u = __shfl_up(sv, o, 64);
            if (lane >= o) sv += u;
        }
        if (lane == 63) wtotS[tid >> 6] = sv;
    }
    __syncthreads();
    if (tid < TT) {
        if (tid >= 64) sv += wtotS[0];
        cumS[tid] = sv;
    }
    __syncthreads();

    // ---- length-regulate gather: idx[p] = #{t : cum[t] <= p} ----
    const int total = cumS[TT - 1];
    float4* outB4 = reinterpret_cast<float4*>(outg) + (size_t)b * (MAXLEN * NL4);
    for (int pp = 0; pp < 20; ++pp) {
        const int p = wid * 20 + pp;     // 4 waves x 20 frames = 80
        int lo = 0, hi = TT;
        while (lo < hi) {                // uniform across the wave
            const int mid = (lo + hi) >> 1;
            if (cumS[mid] <= p) lo = mid + 1; else hi = mid;
        }
        float4 v = make_float4(0.f, 0.f, 0.f, 0.f);
        if (p < total) {
            const int src = (lo < TT) ? lo : (TT - 1);
            v = encB4[src * NL4 + lane];
        }
        outB4[p * NL4 + lane] = v;
    }
}

extern "C" void kernel_launch(void* const* d_in, const int* in_sizes, int n_in,
                              void* d_out, int out_size, void* d_ws, size_t ws_size,
                              hipStream_t stream) {
    const float* enc = (const float*)d_in[0];
    const float* w1  = (const float*)d_in[1];
    const float* b1  = (const float*)d_in[2];
    const float* w2  = (const float*)d_in[3];
    const float* b2  = (const float*)d_in[4];
    const float* gam = (const float*)d_in[5];
    const float* bet = (const float*)d_in[6];
    const float* dw  = (const float*)d_in[7];
    const float* db  = (const float*)d_in[8];
    float* out = (float*)d_out;

    const int B = in_sizes[0] / (TT * CC);   // 2048
    hipLaunchKernelGGL(va_fused, dim3(B), dim3(256), 0, stream,
                       enc, w1, b1, w2, b2, gam, bet, dw, db, out);
}

// Round 2
// 1925.247 us; speedup vs baseline: 1.6932x; 1.6932x over previous
//
#include <hip/hip_runtime.h>
#include <hip/hip_bf16.h>
#include <math.h>

#define TT 128      // time steps
#define CC 256      // channels
#define MAXLEN 80
#define KSTEPS 24   // 3 taps * 8 k-blocks of 32

typedef __attribute__((ext_vector_type(8))) short short8v;  // 8 bf16 = 4 VGPR
typedef __attribute__((ext_vector_type(4))) float f32x4;

// RTNE f32 -> bf16 step: returns biased int whose top 16 bits are the bf16,
// and (t & 0xffff0000) is the rounded value as f32 bits.
__device__ __forceinline__ unsigned bfrnd(unsigned u) {
    return u + 0x7fffu + ((u >> 16) & 1u);
}

// ---------------- prep: split weights into bf16 h/m/l planes in B-fragment order
// idx = ((((cv*3+tap)*8+kk2)*3+plane)*16+nfg)*64+lane ; each entry = 8 bf16 (k-contig)
__global__ void va_prep(const float* __restrict__ w1, const float* __restrict__ w2,
                        short8v* __restrict__ wsB)
{
    const int idx = blockIdx.x * 256 + threadIdx.x;   // 0 .. 147455
    const int lane = idx & 63;
    int q = idx >> 6;
    const int nfg = q & 15;  q >>= 4;
    const int plane = q % 3; q /= 3;
    const int kk2 = q & 7;   q >>= 3;
    const int tap = q % 3;
    const int cv  = q / 3;
    const float* w = cv ? w2 : w1;
    const int co  = nfg * 16 + (lane & 15);
    const int ci0 = kk2 * 32 + (lane >> 4) * 8;
    short8v out;
    #pragma unroll
    for (int j = 0; j < 8; ++j) {
        const float x = w[tap * (CC * CC) + (ci0 + j) * CC + co];
        const unsigned u  = __builtin_bit_cast(unsigned, x);
        const unsigned t1 = bfrnd(u);
        const float hf = __builtin_bit_cast(float, t1 & 0xffff0000u);
        const float r1 = x - hf;
        const unsigned u2 = __builtin_bit_cast(unsigned, r1);
        const unsigned t2 = bfrnd(u2);
        const float mv = __builtin_bit_cast(float, t2 & 0xffff0000u);
        const float r2 = r1 - mv;
        const unsigned u3 = __builtin_bit_cast(unsigned, r2);
        const unsigned t3 = bfrnd(u3);
        const unsigned short h = (unsigned short)(t1 >> 16);
        const unsigned short m = (unsigned short)(t2 >> 16);
        const unsigned short l = (unsigned short)(t3 >> 16);
        out[j] = (short)(plane == 0 ? h : (plane == 1 ? m : l));
    }
    wsB[idx] = out;
}

// ---------------- fused variance adaptor, MFMA core
// 1 WG per batch element, 4 waves. Wave w owns N-cols [w*64, w*64+64), all M=128 rows.
// LDS xs: f32 activations at slot t+1 (slots 0,129 = zero halo), XOR-swizzled:
//   float4 index: slot*64 + (c4 ^ (slot&7))   (c4 = ch/4)
__global__ __launch_bounds__(256, 1)
void va_mfma(const float* __restrict__ enc,
             const float* __restrict__ b1g, const float* __restrict__ b2g,
             const float* __restrict__ gg,  const float* __restrict__ bbg,
             const float* __restrict__ dwg, const float* __restrict__ dbg,
             const short8v* __restrict__ wsB,
             float* __restrict__ outg)
{
    __shared__ f32x4 xs4[130 * 64];     // 133120 B
    __shared__ float sumS[4][TT];
    __shared__ float muS[TT];
    __shared__ float rsS[TT];
    __shared__ int   durS[TT];
    __shared__ int   cumS[TT];
    __shared__ int   wtotS[2];

    float* xs = (float*)xs4;
    const int b    = blockIdx.x;
    const int tid  = threadIdx.x;
    const int wid  = tid >> 6;
    const int lane = tid & 63;
    const int l15  = lane & 15;
    const int lg   = lane >> 4;

    const f32x4* encB4 = reinterpret_cast<const f32x4*>(enc) + (size_t)b * (TT * 64);

    // ---- stage enc -> xs (swizzled), zero halo ----
    for (int m2 = tid; m2 < 130 * 64; m2 += 256) {
        const int slot = m2 >> 6;
        const int c4 = m2 & 63;
        f32x4 v = {0.f, 0.f, 0.f, 0.f};
        if (slot >= 1 && slot <= TT) v = encB4[(slot - 1) * 64 + c4];
        xs4[slot * 64 + (c4 ^ (slot & 7))] = v;
    }
    __syncthreads();

    f32x4 acc[8][4];   // [mf][nf]: row = mf*16 + lg*4 + r, col = wid*64 + nf*16 + l15

    float gv[4], bvv[4];
    #pragma unroll
    for (int nf = 0; nf < 4; ++nf) {
        gv[nf]  = gg[wid * 64 + nf * 16 + l15];
        bvv[nf] = bbg[wid * 64 + nf * 16 + l15];
    }

    auto convpass = [&](int cv, const float* __restrict__ biasp, bool first) {
        #pragma unroll
        for (int nf = 0; nf < 4; ++nf) {
            const float bz = biasp[wid * 64 + nf * 16 + l15];
            const f32x4 b4 = {bz, bz, bz, bz};
            #pragma unroll
            for (int mf = 0; mf < 8; ++mf) acc[mf][nf] = b4;
        }

        short8v B0[12], B1[12];   // [plane*4 + nf]
        auto loadB = [&](short8v (&Bp)[12], int ks) {
            const int tap = ks >> 3, kk2 = ks & 7;
            const int fb = ((cv * 3 + tap) * 8 + kk2) * 3;
            #pragma unroll
            for (int p = 0; p < 3; ++p)
                #pragma unroll
                for (int nf = 0; nf < 4; ++nf)
                    Bp[p * 4 + nf] = wsB[(size_t)((fb + p) * 16 + (wid * 4 + nf)) * 64 + lane];
        };
        auto doK = [&](const short8v (&Bp)[12], int ks) {
            const int tap = ks >> 3, kk2 = ks & 7;
            #pragma unroll
            for (int mf = 0; mf < 8; ++mf) {
                const int slot = mf * 16 + l15 + tap;   // A row = mf*16+l15, slot = row+tap
                const int c4 = kk2 * 8 + lg * 2;        // k = kk2*32 + lg*8 + j
                const int sw = slot & 7;
                const f32x4 a0 = xs4[slot * 64 + (c4 ^ sw)];
                const f32x4 a1 = xs4[slot * 64 + ((c4 + 1) ^ sw)];
                const float av[8] = {a0.x, a0.y, a0.z, a0.w, a1.x, a1.y, a1.z, a1.w};
                short8v Ah, Am, Al;
                #pragma unroll
                for (int j = 0; j < 8; ++j) {
                    const float x = av[j];
                    const unsigned u  = __builtin_bit_cast(unsigned, x);
                    const unsigned t1 = bfrnd(u);
                    const float hf = __builtin_bit_cast(float, t1 & 0xffff0000u);
                    Ah[j] = (short)(t1 >> 16);
                    const float r1 = x - hf;
                    const unsigned u2 = __builtin_bit_cast(unsigned, r1);
                    const unsigned t2 = bfrnd(u2);
                    const float mv = __builtin_bit_cast(float, t2 & 0xffff0000u);
                    Am[j] = (short)(t2 >> 16);
                    const float r2 = r1 - mv;
                    const unsigned u3 = __builtin_bit_cast(unsigned, r2);
                    const unsigned t3 = bfrnd(u3);
                    Al[j] = (short)(t3 >> 16);
                }
                #pragma unroll
                for (int nf = 0; nf < 4; ++nf) {
                    f32x4 c = acc[mf][nf];
                    c = __builtin_amdgcn_mfma_f32_16x16x32_bf16(Ah, Bp[0 * 4 + nf], c, 0, 0, 0);
                    c = __builtin_amdgcn_mfma_f32_16x16x32_bf16(Ah, Bp[1 * 4 + nf], c, 0, 0, 0);
                    c = __builtin_amdgcn_mfma_f32_16x16x32_bf16(Am, Bp[0 * 4 + nf], c, 0, 0, 0);
                    c = __builtin_amdgcn_mfma_f32_16x16x32_bf16(Ah, Bp[2 * 4 + nf], c, 0, 0, 0);
                    c = __builtin_amdgcn_mfma_f32_16x16x32_bf16(Al, Bp[0 * 4 + nf], c, 0, 0, 0);
                    c = __builtin_amdgcn_mfma_f32_16x16x32_bf16(Am, Bp[1 * 4 + nf], c, 0, 0, 0);
                    acc[mf][nf] = c;
                }
            }
        };

        loadB(B0, 0);
        #pragma unroll 1
        for (int ks = 0; ks < KSTEPS; ks += 2) {
            loadB(B1, ks + 1);
            doK(B0, ks);
            if (ks + 2 < KSTEPS) loadB(B0, ks + 2);
            doK(B1, ks + 1);
        }

        // relu
        #pragma unroll
        for (int mf = 0; mf < 8; ++mf)
            #pragma unroll
            for (int nf = 0; nf < 4; ++nf) {
                f32x4 v = acc[mf][nf];
                v.x = fmaxf(v.x, 0.f); v.y = fmaxf(v.y, 0.f);
                v.z = fmaxf(v.z, 0.f); v.w = fmaxf(v.w, 0.f);
                acc[mf][nf] = v;
            }

        // LN pass 1: row sums (per-wave partial over 64 cols, combine via LDS)
        #pragma unroll
        for (int mf = 0; mf < 8; ++mf)
            #pragma unroll
            for (int r = 0; r < 4; ++r) {
                float s = acc[mf][0][r] + acc[mf][1][r] + acc[mf][2][r] + acc[mf][3][r];
                s += __shfl_xor(s, 1, 64); s += __shfl_xor(s, 2, 64);
                s += __shfl_xor(s, 4, 64); s += __shfl_xor(s, 8, 64);
                if (l15 == 0) sumS[wid][mf * 16 + lg * 4 + r] = s;
            }
        __syncthreads();
        if (tid < TT)
            muS[tid] = (sumS[0][tid] + sumS[1][tid] + sumS[2][tid] + sumS[3][tid]) * (1.f / 256.f);
        __syncthreads();
        // LN pass 2: variance (two-pass, matches reference)
        #pragma unroll
        for (int mf = 0; mf < 8; ++mf)
            #pragma unroll
            for (int r = 0; r < 4; ++r) {
                const float mu = muS[mf * 16 + lg * 4 + r];
                float q = 0.f;
                #pragma unroll
                for (int nf = 0; nf < 4; ++nf) {
                    const float d = acc[mf][nf][r] - mu;
                    q = fmaf(d, d, q);
                }
                q += __shfl_xor(q, 1, 64); q += __shfl_xor(q, 2, 64);
                q += __shfl_xor(q, 4, 64); q += __shfl_xor(q, 8, 64);
                if (l15 == 0) sumS[wid][mf * 16 + lg * 4 + r] = q;
            }
        __syncthreads();
        if (tid < TT) {
            const float var = (sumS[0][tid] + sumS[1][tid] + sumS[2][tid] + sumS[3][tid]) * (1.f / 256.f);
            rsS[tid] = 1.0f / sqrtf(var + 1e-6f);
        }
        __syncthreads();
        // normalize; conv1 also writes x1 back to xs (swizzled)
        #pragma unroll
        for (int mf = 0; mf < 8; ++mf)
            #pragma unroll
            for (int r = 0; r < 4; ++r) {
                const int row = mf * 16 + lg * 4 + r;
                const float mu = muS[row];
                const float rs = rsS[row];
                if (first) {
                    const int slot = row + 1;
                    const int sw = (slot & 7) << 2;
                    #pragma unroll
                    for (int nf = 0; nf < 4; ++nf) {
                        const int ch = wid * 64 + nf * 16 + l15;
                        const float v = (acc[mf][nf][r] - mu) * rs * gv[nf] + bvv[nf];
                        xs[slot * 256 + (ch ^ sw)] = v;
                    }
                } else {
                    #pragma unroll
                    for (int nf = 0; nf < 4; ++nf)
                        acc[mf][nf][r] = (acc[mf][nf][r] - mu) * rs * gv[nf] + bvv[nf];
                }
            }
    };

    // ---- conv1 ----
    convpass(0, b1g, true);
    // zero halo slots 0 and 129 (held stale enc values)
    if (tid < 64) {
        const f32x4 z = {0.f, 0.f, 0.f, 0.f};
        xs4[0 * 64 + tid]   = z;
        xs4[129 * 64 + tid] = z;
    }
    __syncthreads();
    // ---- conv2 ----
    convpass(1, b2g, false);

    // ---- dense -> durations ----
    {
        float dv[4];
        #pragma unroll
        for (int nf = 0; nf < 4; ++nf) dv[nf] = dwg[wid * 64 + nf * 16 + l15];
        #pragma unroll
        for (int mf = 0; mf < 8; ++mf)
            #pragma unroll
            for (int r = 0; r < 4; ++r) {
                float p = acc[mf][0][r] * dv[0] + acc[mf][1][r] * dv[1]
                        + acc[mf][2][r] * dv[2] + acc[mf][3][r] * dv[3];
                p += __shfl_xor(p, 1, 64); p += __shfl_xor(p, 2, 64);
                p += __shfl_xor(p, 4, 64); p += __shfl_xor(p, 8, 64);
                if (l15 == 0) sumS[wid][mf * 16 + lg * 4 + r] = p;
            }
        __syncthreads();
        if (tid < TT) {
            const float pd = sumS[0][tid] + sumS[1][tid] + sumS[2][tid] + sumS[3][tid] + dbg[0];
            const float dcl = fminf(fmaxf(pd, 0.0f), 75.0f);
            durS[tid] = (int)rintf(dcl);   // RTNE matches jnp.round
        }
        __syncthreads();
    }

    // ---- inclusive cumsum over T=128 (two-wave scan) ----
    int sv = 0;
    if (tid < TT) {
        sv = durS[tid];
        #pragma unroll
        for (int o = 1; o < 64; o <<= 1) {
            const int u = __shfl_up(sv, o, 64);
            if (lane >= o) sv += u;
        }
        if (lane == 63) wtotS[tid >> 6] = sv;
    }
    __syncthreads();
    if (tid < TT) {
        if (tid >= 64) sv += wtotS[0];
        cumS[tid] = sv;
    }
    __syncthreads();

    // ---- length-regulate gather ----
    const int total = cumS[TT - 1];
    f32x4* outB4 = reinterpret_cast<f32x4*>(outg) + (size_t)b * (MAXLEN * 64);
    for (int pp = 0; pp < 20; ++pp) {
        const int p = wid * 20 + pp;
        int lo = 0, hi = TT;
        while (lo < hi) {
            const int mid = (lo + hi) >> 1;
            if (cumS[mid] <= p) lo = mid + 1; else hi = mid;
        }
        f32x4 v = {0.f, 0.f, 0.f, 0.f};
        if (p < total) {
            const int src = (lo < TT) ? lo : (TT - 1);
            v = encB4[src * 64 + lane];
        }
        outB4[p * 64 + lane] = v;
    }
}

extern "C" void kernel_launch(void* const* d_in, const int* in_sizes, int n_in,
                              void* d_out, int out_size, void* d_ws, size_t ws_size,
                              hipStream_t stream) {
    const float* enc = (const float*)d_in[0];
    const float* w1  = (const float*)d_in[1];
    const float* b1  = (const float*)d_in[2];
    const float* w2  = (const float*)d_in[3];
    const float* b2  = (const float*)d_in[4];
    const float* gam = (const float*)d_in[5];
    const float* bet = (const float*)d_in[6];
    const float* dw  = (const float*)d_in[7];
    const float* db  = (const float*)d_in[8];
    float* out = (float*)d_out;
    short8v* wsB = (short8v*)d_ws;   // 2 convs * 1152 frags * 64 lanes * 16 B = 2.36 MB

    const int B = in_sizes[0] / (TT * CC);   // 2048
    hipLaunchKernelGGL(va_prep, dim3(576), dim3(256), 0, stream, w1, w2, wsB);
    hipLaunchKernelGGL(va_mfma, dim3(B), dim3(256), 0, stream,
                       enc, b1, b2, gam, bet, dw, db, wsB, out);
}

// Round 3
// 771.836 us; speedup vs baseline: 4.2234x; 2.4944x over previous
//
#include <hip/hip_runtime.h>
#include <hip/hip_bf16.h>
#include <math.h>

#define TT 128      // time steps
#define CC 256      // channels
#define MAXLEN 80
#define KSTEPS 24   // 3 taps * 8 k-blocks of 32
#define SLOTS 130   // rows 0..127 at slot r+1, zero halo at 0 and 129
#define NCH16 32    // 16B chunks (8 f16) per 256-ch row

typedef __attribute__((ext_vector_type(8))) _Float16 half8v;  // 8 f16 = 4 VGPR
typedef __attribute__((ext_vector_type(4))) float f32x4;

#define MSCALE 4096.0f       // 2^12: keeps m-plane out of f16 denormal range
#define MINV   (1.0f/4096.0f)

// swizzled chunk index within a plane: 16B chunk c16 of slot
__device__ __forceinline__ int chunk(int slot, int c16) {
    return slot * NCH16 + (c16 ^ (slot & 7));
}

// ---------------- prep: split conv weights into f16 h/m planes (m scaled 2^12)
// in MFMA B-fragment order. frag = (((cv*3+tap)*8+kk2)*2+plane);
// entry idx = (frag*16 + nfg)*64 + lane; each entry = 8 f16 (k-contig).
__global__ void va_prep(const float* __restrict__ w1, const float* __restrict__ w2,
                        half8v* __restrict__ wsB)
{
    const int idx = blockIdx.x * 256 + threadIdx.x;   // 0 .. 98303
    const int lane = idx & 63;
    int q = idx >> 6;
    const int nfg = q & 15;   q >>= 4;
    const int plane = q & 1;  q >>= 1;
    const int kk2 = q & 7;    q >>= 3;
    const int tap = q % 3;
    const int cv  = q / 3;
    const float* w = cv ? w2 : w1;
    const int co  = nfg * 16 + (lane & 15);
    const int ci0 = kk2 * 32 + (lane >> 4) * 8;
    half8v out;
    #pragma unroll
    for (int j = 0; j < 8; ++j) {
        const float x = w[tap * (CC * CC) + (ci0 + j) * CC + co];
        const _Float16 h = (_Float16)x;
        if (plane == 0) out[j] = h;
        else            out[j] = (_Float16)((x - (float)h) * MSCALE);
    }
    wsB[idx] = out;
}

// ---------------- fused variance adaptor, f16 2-plane MFMA core
// 1 WG (512 thr = 8 waves) per batch element. Wave w owns N-cols [w*32, w*32+32).
// LDS planes P[2]: f16 activations, slot = row+1, XOR-swizzled 16B chunks.
__global__ __launch_bounds__(512, 2)
void va_mfma(const float* __restrict__ enc,
             const float* __restrict__ b1g, const float* __restrict__ b2g,
             const float* __restrict__ gg,  const float* __restrict__ bbg,
             const float* __restrict__ dwg, const float* __restrict__ dbg,
             const half8v* __restrict__ wsB,
             float* __restrict__ outg)
{
    __shared__ half8v P[2][SLOTS * NCH16];   // 133,120 B
    __shared__ float sumS[8][TT];            // 4 KB
    __shared__ float muS[TT];
    __shared__ float rsS[TT];
    __shared__ int   durS[TT];
    __shared__ int   cumS[TT];
    __shared__ int   wtotS[2];

    const int b    = blockIdx.x;
    const int tid  = threadIdx.x;
    const int wid  = tid >> 6;      // 0..7
    const int lane = tid & 63;
    const int l15  = lane & 15;
    const int lg   = lane >> 4;

    const f32x4* encB4 = reinterpret_cast<const f32x4*>(enc) + (size_t)b * (TT * 64);

    // ---- stage: read enc rows, split to f16 h/m planes, write swizzled ----
    for (int m = tid; m < SLOTS * NCH16; m += 512) {
        const int slot = m >> 5;
        const int c16  = m & 31;
        half8v h8, m8;
        if (slot >= 1 && slot <= TT) {
            const f32x4* src = encB4 + (slot - 1) * 64 + c16 * 2;
            const f32x4 v0 = src[0], v1 = src[1];
            #pragma unroll
            for (int j = 0; j < 8; ++j) {
                const float x = (j < 4) ? v0[j] : v1[j - 4];
                const _Float16 h = (_Float16)x;
                h8[j] = h;
                m8[j] = (_Float16)((x - (float)h) * MSCALE);
            }
        } else {
            #pragma unroll
            for (int j = 0; j < 8; ++j) { h8[j] = (_Float16)0.f; m8[j] = (_Float16)0.f; }
        }
        const int ci = chunk(slot, c16);
        P[0][ci] = h8;
        P[1][ci] = m8;
    }
    __syncthreads();

    f32x4 accH[8][2];   // row = mf*16 + lg*4 + r, col = wid*32 + nf*16 + l15
    f32x4 accM[8][2];   // scaled-m cross terms (x 2^12)

    float gv[2], bvv[2];
    #pragma unroll
    for (int nf = 0; nf < 2; ++nf) {
        gv[nf]  = gg[wid * 32 + nf * 16 + l15];
        bvv[nf] = bbg[wid * 32 + nf * 16 + l15];
    }

    auto convpass = [&](int cv, const float* __restrict__ biasp, bool first) {
        #pragma unroll
        for (int nf = 0; nf < 2; ++nf) {
            const float bz = biasp[wid * 32 + nf * 16 + l15];
            const f32x4 b4 = {bz, bz, bz, bz};
            const f32x4 z4 = {0.f, 0.f, 0.f, 0.f};
            #pragma unroll
            for (int mf = 0; mf < 8; ++mf) { accH[mf][nf] = b4; accM[mf][nf] = z4; }
        }

        half8v B0[4], B1[4];   // [plane*2 + nf]
        auto loadB = [&](half8v (&Bp)[4], int ks) {
            const int tap = ks >> 3, kk2 = ks & 7;
            #pragma unroll
            for (int p = 0; p < 2; ++p) {
                const int frag = (((cv * 3 + tap) * 8 + kk2) * 2 + p);
                #pragma unroll
                for (int nf = 0; nf < 2; ++nf)
                    Bp[p * 2 + nf] = wsB[(size_t)(frag * 16 + (wid * 2 + nf)) * 64 + lane];
            }
        };
        auto doK = [&](const half8v (&Bp)[4], int ks) {
            const int tap = ks >> 3, kk2 = ks & 7;
            #pragma unroll
            for (int mf = 0; mf < 8; ++mf) {
                const int slot = mf * 16 + l15 + tap;   // A row = mf*16+l15
                const int c16  = kk2 * 4 + lg;          // k = kk2*32 + lg*8 + j
                const int ci = chunk(slot, c16);
                const half8v Ah = P[0][ci];
                const half8v Am = P[1][ci];
                #pragma unroll
                for (int nf = 0; nf < 2; ++nf) {
                    accH[mf][nf] = __builtin_amdgcn_mfma_f32_16x16x32_f16(Ah, Bp[0 * 2 + nf], accH[mf][nf], 0, 0, 0);
                    accM[mf][nf] = __builtin_amdgcn_mfma_f32_16x16x32_f16(Ah, Bp[1 * 2 + nf], accM[mf][nf], 0, 0, 0);
                    accM[mf][nf] = __builtin_amdgcn_mfma_f32_16x16x32_f16(Am, Bp[0 * 2 + nf], accM[mf][nf], 0, 0, 0);
                }
            }
        };

        loadB(B0, 0);
        #pragma unroll 1
        for (int ks = 0; ks < KSTEPS; ks += 2) {
            loadB(B1, ks + 1);
            doK(B0, ks);
            if (ks + 2 < KSTEPS) loadB(B0, ks + 2);
            doK(B1, ks + 1);
        }

        // combine planes + relu
        #pragma unroll
        for (int mf = 0; mf < 8; ++mf)
            #pragma unroll
            for (int nf = 0; nf < 2; ++nf) {
                f32x4 v;
                #pragma unroll
                for (int e = 0; e < 4; ++e)
                    v[e] = fmaxf(fmaf(accM[mf][nf][e], MINV, accH[mf][nf][e]), 0.f);
                accH[mf][nf] = v;
            }

        // LN pass 1: row sums (per-wave partial over 32 cols, combine via LDS)
        #pragma unroll
        for (int mf = 0; mf < 8; ++mf)
            #pragma unroll
            for (int r = 0; r < 4; ++r) {
                float s = accH[mf][0][r] + accH[mf][1][r];
                s += __shfl_xor(s, 1, 64); s += __shfl_xor(s, 2, 64);
                s += __shfl_xor(s, 4, 64); s += __shfl_xor(s, 8, 64);
                if (l15 == 0) sumS[wid][mf * 16 + lg * 4 + r] = s;
            }
        __syncthreads();
        if (tid < TT) {
            float t = 0.f;
            #pragma unroll
            for (int w = 0; w < 8; ++w) t += sumS[w][tid];
            muS[tid] = t * (1.f / 256.f);
        }
        __syncthreads();
        // LN pass 2: variance (two-pass, matches reference)
        #pragma unroll
        for (int mf = 0; mf < 8; ++mf)
            #pragma unroll
            for (int r = 0; r < 4; ++r) {
                const float mu = muS[mf * 16 + lg * 4 + r];
                float q = 0.f;
                #pragma unroll
                for (int nf = 0; nf < 2; ++nf) {
                    const float d = accH[mf][nf][r] - mu;
                    q = fmaf(d, d, q);
                }
                q += __shfl_xor(q, 1, 64); q += __shfl_xor(q, 2, 64);
                q += __shfl_xor(q, 4, 64); q += __shfl_xor(q, 8, 64);
                if (l15 == 0) sumS[wid][mf * 16 + lg * 4 + r] = q;
            }
        __syncthreads();
        if (tid < TT) {
            float t = 0.f;
            #pragma unroll
            for (int w = 0; w < 8; ++w) t += sumS[w][tid];
            rsS[tid] = 1.0f / sqrtf(t * (1.f / 256.f) + 1e-6f);
        }
        __syncthreads();
        // normalize; conv1 writes x1 back to planes (f16 h/m, swizzled scatter)
        _Float16* Ph = (_Float16*)&P[0][0];
        _Float16* Pm = (_Float16*)&P[1][0];
        #pragma unroll
        for (int mf = 0; mf < 8; ++mf)
            #pragma unroll
            for (int r = 0; r < 4; ++r) {
                const int row = mf * 16 + lg * 4 + r;
                const float mu = muS[row];
                const float rs = rsS[row];
                #pragma unroll
                for (int nf = 0; nf < 2; ++nf) {
                    const float v = (accH[mf][nf][r] - mu) * rs * gv[nf] + bvv[nf];
                    if (first) {
                        const int col = wid * 32 + nf * 16 + l15;
                        const int slot = row + 1;
                        const int off = chunk(slot, col >> 3) * 8 + (col & 7);
                        const _Float16 h = (_Float16)v;
                        Ph[off] = h;
                        Pm[off] = (_Float16)((v - (float)h) * MSCALE);
                    } else {
                        accH[mf][nf][r] = v;
                    }
                }
            }
    };

    // ---- conv1 (writes x1 planes) ----
    convpass(0, b1g, true);
    __syncthreads();
    // ---- conv2 ----
    convpass(1, b2g, false);

    // ---- dense -> durations ----
    {
        float dv[2];
        #pragma unroll
        for (int nf = 0; nf < 2; ++nf) dv[nf] = dwg[wid * 32 + nf * 16 + l15];
        #pragma unroll
        for (int mf = 0; mf < 8; ++mf)
            #pragma unroll
            for (int r = 0; r < 4; ++r) {
                float p = accH[mf][0][r] * dv[0] + accH[mf][1][r] * dv[1];
                p += __shfl_xor(p, 1, 64); p += __shfl_xor(p, 2, 64);
                p += __shfl_xor(p, 4, 64); p += __shfl_xor(p, 8, 64);
                if (l15 == 0) sumS[wid][mf * 16 + lg * 4 + r] = p;
            }
        __syncthreads();
        if (tid < TT) {
            float t = 0.f;
            #pragma unroll
            for (int w = 0; w < 8; ++w) t += sumS[w][tid];
            const float pd  = t + dbg[0];
            const float dcl = fminf(fmaxf(pd, 0.0f), 75.0f);
            durS[tid] = (int)rintf(dcl);   // RTNE matches jnp.round
        }
        __syncthreads();
    }

    // ---- inclusive cumsum over T=128 (two-wave scan) ----
    int sv = 0;
    if (tid < TT) {
        sv = durS[tid];
        #pragma unroll
        for (int o = 1; o < 64; o <<= 1) {
            const int u = __shfl_up(sv, o, 64);
            if (lane >= o) sv += u;
        }
        if (lane == 63) wtotS[tid >> 6] = sv;
    }
    __syncthreads();
    if (tid < TT) {
        if (tid >= 64) sv += wtotS[0];
        cumS[tid] = sv;
    }
    __syncthreads();

    // ---- length-regulate gather ----
    const int total = cumS[TT - 1];
    f32x4* outB4 = reinterpret_cast<f32x4*>(outg) + (size_t)b * (MAXLEN * 64);
    for (int pp = 0; pp < 10; ++pp) {
        const int p = wid * 10 + pp;     // 8 waves x 10 frames = 80
        int lo = 0, hi = TT;
        while (lo < hi) {                // uniform across the wave
            const int mid = (lo + hi) >> 1;
            if (cumS[mid] <= p) lo = mid + 1; else hi = mid;
        }
        f32x4 v = {0.f, 0.f, 0.f, 0.f};
        if (p < total) {
            const int src = (lo < TT) ? lo : (TT - 1);
            v = encB4[src * 64 + lane];
        }
        outB4[p * 64 + lane] = v;
    }
}

extern "C" void kernel_launch(void* const* d_in, const int* in_sizes, int n_in,
                              void* d_out, int out_size, void* d_ws, size_t ws_size,
                              hipStream_t stream) {
    const float* enc = (const float*)d_in[0];
    const float* w1  = (const float*)d_in[1];
    const float* b1  = (const float*)d_in[2];
    const float* w2  = (const float*)d_in[3];
    const float* b2  = (const float*)d_in[4];
    const float* gam = (const float*)d_in[5];
    const float* bet = (const float*)d_in[6];
    const float* dw  = (const float*)d_in[7];
    const float* db  = (const float*)d_in[8];
    float* out = (float*)d_out;
    half8v* wsB = (half8v*)d_ws;   // 98304 frags * 16 B = 1.57 MB

    const int B = in_sizes[0] / (TT * CC);   // 2048
    hipLaunchKernelGGL(va_prep, dim3(384), dim3(256), 0, stream, w1, w2, wsB);
    hipLaunchKernelGGL(va_mfma, dim3(B), dim3(512), 0, stream,
                       enc, b1, b2, gam, bet, dw, db, wsB, out);
}

// Round 5
// 654.695 us; speedup vs baseline: 4.9790x; 1.1789x over previous
//
#include <hip/hip_runtime.h>
#include <hip/hip_bf16.h>
#include <math.h>

#define TT 128      // time steps
#define CC 256      // channels
#define MAXLEN 80
#define KSTEPS 24   // 3 taps * 8 k-blocks of 32
#define SLOTS 130   // rows 0..127 at slot r+1, zero halo at 0 and 129
#define NCH16 32    // 16B chunks (8 f16) per 256-ch row

typedef __attribute__((ext_vector_type(8))) _Float16 half8v;  // 8 f16 = 4 VGPR
typedef __attribute__((ext_vector_type(2))) _Float16 half2v;
typedef __attribute__((ext_vector_type(4))) float f32x4;

#define MSCALE 4096.0f       // 2^12: keeps m-plane out of f16 denormal range
#define MINV   (1.0f/4096.0f)

__device__ __forceinline__ int chunkidx(int slot, int c16) {
    return slot * NCH16 + (c16 ^ (slot & 7));
}

// h = RTZ f16 pair (pkrtz); m = RTNE f16 of (x-h)*4096.
// (x-h) is exact in f32 (Sterbenz); *4096 exact; the fma computes it in one
// rounding-free step, so m captures h's rounding error exactly.
__device__ __forceinline__ void split2(float x0, float x1, half2v& h, half2v& m) {
    h = __builtin_bit_cast(half2v, __builtin_amdgcn_cvt_pkrtz(x0, x1));
    m.x = (_Float16)fmaf((float)h.x, -MSCALE, x0 * MSCALE);
    m.y = (_Float16)fmaf((float)h.y, -MSCALE, x1 * MSCALE);
}

// ---------------- prep: split conv weights into f16 h/m planes (m scaled 2^12,
// both RTNE) in MFMA B-fragment order. frag = (((cv*3+tap)*8+kk2)*2+plane);
// entry idx = (frag*16 + nfg)*64 + lane; each entry = 8 f16 (k-contig).
__global__ void va_prep(const float* __restrict__ w1, const float* __restrict__ w2,
                        half8v* __restrict__ wsB)
{
    const int idx = blockIdx.x * 256 + threadIdx.x;   // 0 .. 98303
    const int lane = idx & 63;
    int q = idx >> 6;
    const int nfg = q & 15;   q >>= 4;
    const int plane = q & 1;  q >>= 1;
    const int kk2 = q & 7;    q >>= 3;
    const int tap = q % 3;
    const int cv  = q / 3;
    const float* w = cv ? w2 : w1;
    const int co  = nfg * 16 + (lane & 15);
    const int ci0 = kk2 * 32 + (lane >> 4) * 8;
    half8v out;
    #pragma unroll
    for (int j = 0; j < 8; ++j) {
        const float x = w[tap * (CC * CC) + (ci0 + j) * CC + co];
        const _Float16 h = (_Float16)x;           // RTNE
        if (plane == 0) out[j] = h;
        else            out[j] = (_Float16)((x - (float)h) * MSCALE);
    }
    wsB[idx] = out;
}

// ---------------- fused variance adaptor, f16 2-plane MFMA core
// 1 WG (512 thr = 8 waves) per batch element. Wave w: mg = w>>2 (row half),
// ng = w&3 (col quarter): tile = rows [mg*64,+64) x cols [ng*64,+64).
// LDS planes P[2]: f16 activations, slot = row+1, XOR-swizzled 16B chunks.
__global__ __launch_bounds__(512, 2)
void va_mfma(const float* __restrict__ enc,
             const float* __restrict__ b1g, const float* __restrict__ b2g,
             const float* __restrict__ gg,  const float* __restrict__ bbg,
             const float* __restrict__ dwg, const float* __restrict__ dbg,
             const half8v* __restrict__ wsB,
             float* __restrict__ outg)
{
    __shared__ half8v P[2][SLOTS * NCH16];   // 133,120 B
    __shared__ float sumS[4][TT];            // 2 KB  (indexed [ng][row])
    __shared__ float sumQ[4][TT];            // 2 KB
    __shared__ float muS[TT];
    __shared__ float rsS[TT];
    __shared__ int   durS[TT];
    __shared__ int   cumS[TT];
    __shared__ int   wtotS[2];

    const int b    = blockIdx.x;
    const int tid  = threadIdx.x;
    const int wid  = tid >> 6;      // 0..7
    const int lane = tid & 63;
    const int l15  = lane & 15;
    const int lg   = lane >> 4;
    const int MGr  = (wid >> 2) * 64;   // row base of this wave
    const int NG   = wid & 3;           // col quarter
    const int NGc  = NG * 64;           // col base

    const f32x4* encB4 = reinterpret_cast<const f32x4*>(enc) + (size_t)b * (TT * 64);

    // ---- stage: read enc rows, split to f16 h/m planes, write swizzled ----
    for (int m2 = tid; m2 < SLOTS * NCH16; m2 += 512) {
        const int slot = m2 >> 5;
        const int c16  = m2 & 31;
        half8v h8, m8;
        if (slot >= 1 && slot <= TT) {
            const f32x4* src = encB4 + (slot - 1) * 64 + c16 * 2;
            const f32x4 v0 = src[0], v1 = src[1];
            half2v hp, mp;
            split2(v0.x, v0.y, hp, mp); h8[0]=hp.x; h8[1]=hp.y; m8[0]=mp.x; m8[1]=mp.y;
            split2(v0.z, v0.w, hp, mp); h8[2]=hp.x; h8[3]=hp.y; m8[2]=mp.x; m8[3]=mp.y;
            split2(v1.x, v1.y, hp, mp); h8[4]=hp.x; h8[5]=hp.y; m8[4]=mp.x; m8[5]=mp.y;
            split2(v1.z, v1.w, hp, mp); h8[6]=hp.x; h8[7]=hp.y; m8[6]=mp.x; m8[7]=mp.y;
        } else {
            #pragma unroll
            for (int j = 0; j < 8; ++j) { h8[j] = (_Float16)0.f; m8[j] = (_Float16)0.f; }
        }
        const int ci = chunkidx(slot, c16);
        P[0][ci] = h8;
        P[1][ci] = m8;
    }
    __syncthreads();

    f32x4 accH[4][4];   // [mf][nf]: row = MGr + mf*16 + lg*4 + r, col = NGc + nf*16 + l15
    f32x4 accM[4][4];   // scaled-m cross terms (x 2^12)

    float gv[4], bvv[4];
    #pragma unroll
    for (int nf = 0; nf < 4; ++nf) {
        gv[nf]  = gg[NGc + nf * 16 + l15];
        bvv[nf] = bbg[NGc + nf * 16 + l15];
    }

    auto convpass = [&](int cv, const float* __restrict__ biasp, bool first) {
        #pragma unroll
        for (int nf = 0; nf < 4; ++nf) {
            const float bz = biasp[NGc + nf * 16 + l15];
            const f32x4 b4 = {bz, bz, bz, bz};
            const f32x4 z4 = {0.f, 0.f, 0.f, 0.f};
            #pragma unroll
            for (int mf = 0; mf < 4; ++mf) { accH[mf][nf] = b4; accM[mf][nf] = z4; }
        }

        half8v B0[8], B1[8];   // [plane*4 + nf]
        auto loadB = [&](half8v (&Bp)[8], int ks) {
            const int tap = ks >> 3, kk2 = ks & 7;
            const int fb = ((cv * 3 + tap) * 8 + kk2) * 2;
            #pragma unroll
            for (int p = 0; p < 2; ++p)
                #pragma unroll
                for (int nf = 0; nf < 4; ++nf)
                    Bp[p * 4 + nf] = wsB[(size_t)((fb + p) * 16 + (NG * 4 + nf)) * 64 + lane];
        };
        auto doK = [&](const half8v (&Bp)[8], int ks) {
            const int tap = ks >> 3, kk2 = ks & 7;
            #pragma unroll
            for (int mf = 0; mf < 4; ++mf) {
                const int slot = MGr + mf * 16 + l15 + tap;   // A row + tap
                const int c16  = kk2 * 4 + lg;                // k = kk2*32 + lg*8 + j
                const int ci = chunkidx(slot, c16);
                const half8v Ah = P[0][ci];
                const half8v Am = P[1][ci];
                #pragma unroll
                for (int nf = 0; nf < 4; ++nf) {
                    accH[mf][nf] = __builtin_amdgcn_mfma_f32_16x16x32_f16(Ah, Bp[nf],     accH[mf][nf], 0, 0, 0);
                    accM[mf][nf] = __builtin_amdgcn_mfma_f32_16x16x32_f16(Ah, Bp[4 + nf], accM[mf][nf], 0, 0, 0);
                    accM[mf][nf] = __builtin_amdgcn_mfma_f32_16x16x32_f16(Am, Bp[nf],     accM[mf][nf], 0, 0, 0);
                }
            }
        };

        loadB(B0, 0);
        #pragma unroll 1
        for (int ks = 0; ks < KSTEPS; ks += 2) {
            loadB(B1, ks + 1);
            doK(B0, ks);
            if (ks + 2 < KSTEPS) loadB(B0, ks + 2);
            doK(B1, ks + 1);
        }

        // combine planes + relu
        #pragma unroll
        for (int mf = 0; mf < 4; ++mf)
            #pragma unroll
            for (int nf = 0; nf < 4; ++nf) {
                f32x4 v;
                #pragma unroll
                for (int e = 0; e < 4; ++e)
                    v[e] = fmaxf(fmaf(accM[mf][nf][e], MINV, accH[mf][nf][e]), 0.f);
                accH[mf][nf] = v;
            }

        // LN single-pass: row sums of x and x^2 (per-wave partial over 64 cols)
        #pragma unroll
        for (int mf = 0; mf < 4; ++mf)
            #pragma unroll
            for (int r = 0; r < 4; ++r) {
                float s = (accH[mf][0][r] + accH[mf][1][r]) + (accH[mf][2][r] + accH[mf][3][r]);
                float q = accH[mf][0][r] * accH[mf][0][r];
                q = fmaf(accH[mf][1][r], accH[mf][1][r], q);
                q = fmaf(accH[mf][2][r], accH[mf][2][r], q);
                q = fmaf(accH[mf][3][r], accH[mf][3][r], q);
                #pragma unroll
                for (int o = 1; o < 16; o <<= 1) {
                    s += __shfl_xor(s, o, 64);
                    q += __shfl_xor(q, o, 64);
                }
                if (l15 == 0) {
                    const int row = MGr + mf * 16 + lg * 4 + r;
                    sumS[NG][row] = s;
                    sumQ[NG][row] = q;
                }
            }
        __syncthreads();
        if (tid < TT) {
            const float S = (sumS[0][tid] + sumS[1][tid]) + (sumS[2][tid] + sumS[3][tid]);
            const float Q = (sumQ[0][tid] + sumQ[1][tid]) + (sumQ[2][tid] + sumQ[3][tid]);
            const float mu = S * (1.f / 256.f);
            const float var = fmaf(-mu, mu, Q * (1.f / 256.f));
            muS[tid] = mu;
            rsS[tid] = 1.0f / sqrtf(var + 1e-6f);
        }
        __syncthreads();
        // normalize; conv1 writes x1 back to planes (f16 h/m, swizzled scatter)
        _Float16* Ph = (_Float16*)&P[0][0];
        _Float16* Pm = (_Float16*)&P[1][0];
        #pragma unroll
        for (int mf = 0; mf < 4; ++mf)
            #pragma unroll
            for (int r = 0; r < 4; ++r) {
                const int row = MGr + mf * 16 + lg * 4 + r;
                const float mu = muS[row];
                const float rs = rsS[row];
                #pragma unroll
                for (int nf = 0; nf < 4; ++nf) {
                    const float v = (accH[mf][nf][r] - mu) * rs * gv[nf] + bvv[nf];
                    if (first) {
                        const int col = NGc + nf * 16 + l15;
                        const int slot = row + 1;
                        const int off = chunkidx(slot, col >> 3) * 8 + (col & 7);
                        const _Float16 h = (_Float16)v;   // RTNE scalar (cheap path)
                        Ph[off] = h;
                        Pm[off] = (_Float16)fmaf((float)h, -MSCALE, v * MSCALE);
                    } else {
                        accH[mf][nf][r] = v;
                    }
                }
            }
    };

    // ---- conv1 (writes x1 planes; halos stay zero) ----
    convpass(0, b1g, true);
    __syncthreads();
    // ---- conv2 ----
    convpass(1, b2g, false);

    // ---- dense -> durations ----
    {
        float dv[4];
        #pragma unroll
        for (int nf = 0; nf < 4; ++nf) dv[nf] = dwg[NGc + nf * 16 + l15];
        #pragma unroll
        for (int mf = 0; mf < 4; ++mf)
            #pragma unroll
            for (int r = 0; r < 4; ++r) {
                float p = (accH[mf][0][r] * dv[0] + accH[mf][1][r] * dv[1])
                        + (accH[mf][2][r] * dv[2] + accH[mf][3][r] * dv[3]);
                #pragma unroll
                for (int o = 1; o < 16; o <<= 1) p += __shfl_xor(p, o, 64);
                if (l15 == 0) sumS[NG][MGr + mf * 16 + lg * 4 + r] = p;
            }
        __syncthreads();
        if (tid < TT) {
            const float pd = (sumS[0][tid] + sumS[1][tid]) + (sumS[2][tid] + sumS[3][tid]) + dbg[0];
            const float dcl = fminf(fmaxf(pd, 0.0f), 75.0f);
            durS[tid] = (int)rintf(dcl);   // RTNE matches jnp.round
        }
        __syncthreads();
    }

    // ---- inclusive cumsum over T=128 (two-wave scan) ----
    int sv = 0;
    if (tid < TT) {
        sv = durS[tid];
        #pragma unroll
        for (int o = 1; o < 64; o <<= 1) {
            const int u = __shfl_up(sv, o, 64);
            if (lane >= o) sv += u;
        }
        if (lane == 63) wtotS[tid >> 6] = sv;
    }
    __syncthreads();
    if (tid < TT) {
        if (tid >= 64) sv += wtotS[0];
        cumS[tid] = sv;
    }
    __syncthreads();

    // ---- length-regulate gather ----
    const int total = cumS[TT - 1];
    f32x4* outB4 = reinterpret_cast<f32x4*>(outg) + (size_t)b * (MAXLEN * 64);
    for (int pp = 0; pp < 10; ++pp) {
        const int p = wid * 10 + pp;     // 8 waves x 10 frames = 80
        int lo = 0, hi = TT;
        while (lo < hi) {                // uniform across the wave
            const int mid = (lo + hi) >> 1;
            if (cumS[mid] <= p) lo = mid + 1; else hi = mid;
        }
        f32x4 v = {0.f, 0.f, 0.f, 0.f};
        if (p < total) {
            const int src = (lo < TT) ? lo : (TT - 1);
            v = encB4[src * 64 + lane];
        }
        outB4[p * 64 + lane] = v;
    }
}

extern "C" void kernel_launch(void* const* d_in, const int* in_sizes, int n_in,
                              void* d_out, int out_size, void* d_ws, size_t ws_size,
                              hipStream_t stream) {
    const float* enc = (const float*)d_in[0];
    const float* w1  = (const float*)d_in[1];
    const float* b1  = (const float*)d_in[2];
    const float* w2  = (const float*)d_in[3];
    const float* b2  = (const float*)d_in[4];
    const float* gam = (const float*)d_in[5];
    const float* bet = (const float*)d_in[6];
    const float* dw  = (const float*)d_in[7];
    const float* db  = (const float*)d_in[8];
    float* out = (float*)d_out;
    half8v* wsB = (half8v*)d_ws;   // 98304 frags * 16 B = 1.57 MB

    const int B = in_sizes[0] / (TT * CC);   // 2048
    hipLaunchKernelGGL(va_prep, dim3(384), dim3(256), 0, stream, w1, w2, wsB);
    hipLaunchKernelGGL(va_mfma, dim3(B), dim3(512), 0, stream,
                       enc, b1, b2, gam, bet, dw, db, wsB, out);
}

// Round 6
// 633.153 us; speedup vs baseline: 5.1484x; 1.0340x over previous
//
#include <hip/hip_runtime.h>
#include <hip/hip_bf16.h>
#include <math.h>

#define TT 128      // time steps
#define CC 256      // channels
#define MAXLEN 80
#define KSTEPS 24   // 3 taps * 8 k-blocks of 32
#define SLOTS 68    // rows base-2 .. base+65 ; slot = (row-base)+2
#define NCH16 32    // 16B chunks (8 f16) per 256-ch row

typedef __attribute__((ext_vector_type(8))) _Float16 half8v;  // 8 f16 = 4 VGPR
typedef __attribute__((ext_vector_type(2))) _Float16 half2v;
typedef __attribute__((ext_vector_type(4))) float f32x4;

#define MSCALE 4096.0f       // 2^12: keeps m-plane out of f16 denormal range
#define MINV   (1.0f/4096.0f)

__device__ __forceinline__ int chunkidx(int slot, int c16) {
    return slot * NCH16 + (c16 ^ (slot & 7));
}

// h = RTZ f16 pair (pkrtz); m = RTNE f16 of (x-h)*4096 (exact residual capture).
__device__ __forceinline__ void split2(float x0, float x1, half2v& h, half2v& m) {
    h = __builtin_bit_cast(half2v, __builtin_amdgcn_cvt_pkrtz(x0, x1));
    m.x = (_Float16)fmaf((float)h.x, -MSCALE, x0 * MSCALE);
    m.y = (_Float16)fmaf((float)h.y, -MSCALE, x1 * MSCALE);
}

// ---------------- prep: split conv weights into f16 h/m planes (m scaled 2^12,
// both RTNE) in MFMA B-fragment order. frag = (((cv*3+tap)*8+kk2)*2+plane);
// entry idx = (frag*16 + nfg)*64 + lane; each entry = 8 f16 (k-contig).
__global__ void va_prep(const float* __restrict__ w1, const float* __restrict__ w2,
                        half8v* __restrict__ wsB)
{
    const int idx = blockIdx.x * 256 + threadIdx.x;   // 0 .. 98303
    const int lane = idx & 63;
    int q = idx >> 6;
    const int nfg = q & 15;   q >>= 4;
    const int plane = q & 1;  q >>= 1;
    const int kk2 = q & 7;    q >>= 3;
    const int tap = q % 3;
    const int cv  = q / 3;
    const float* w = cv ? w2 : w1;
    const int co  = nfg * 16 + (lane & 15);
    const int ci0 = kk2 * 32 + (lane >> 4) * 8;
    half8v out;
    #pragma unroll
    for (int j = 0; j < 8; ++j) {
        const float x = w[tap * (CC * CC) + (ci0 + j) * CC + co];
        const _Float16 h = (_Float16)x;           // RTNE
        if (plane == 0) out[j] = h;
        else            out[j] = (_Float16)((x - (float)h) * MSCALE);
    }
    wsB[idx] = out;
}

// ---------------- conv kernel: 2 WGs per batch, each 64 output rows.
// 256 thr = 4 waves, wave w owns cols [w*64, w*64+64) (nf=4), all M frags.
// conv1 computes x1 rows base-1..base+64 via frags {-1,15,31,47,49} (rows
// 49..62 duplicated -> bitwise-identical double writes, benign).
__global__ __launch_bounds__(256, 2)
void va_conv(const float* __restrict__ enc,
             const float* __restrict__ b1g, const float* __restrict__ b2g,
             const float* __restrict__ gg,  const float* __restrict__ bbg,
             const float* __restrict__ dwg, const float* __restrict__ dbg,
             const half8v* __restrict__ wsB,
             int* __restrict__ durG)
{
    __shared__ half8v P[2][SLOTS * NCH16];   // 69,632 B
    __shared__ float sumS[4][80];
    __shared__ float sumQ[4][80];
    __shared__ float muS[80];
    __shared__ float rsS[80];

    const int bb   = blockIdx.x;
    const int b    = bb >> 1;
    const int base = (bb & 1) << 6;     // 0 or 64
    const int tid  = threadIdx.x;
    const int wid  = tid >> 6;          // 0..3
    const int lane = tid & 63;
    const int l15  = lane & 15;
    const int lg   = lane >> 4;
    const int NGc  = wid * 64;          // col base

    const f32x4* encB4 = reinterpret_cast<const f32x4*>(enc) + (size_t)b * (TT * 64);

    // ---- stage enc rows base-2..base+65 (zero outside [0,TT)) ----
    for (int m2 = tid; m2 < SLOTS * NCH16; m2 += 256) {
        const int slot = m2 >> 5;
        const int c16  = m2 & 31;
        const int ra   = base + slot - 2;
        half8v h8, m8;
        if (ra >= 0 && ra < TT) {
            const f32x4* src = encB4 + ra * 64 + c16 * 2;
            const f32x4 v0 = src[0], v1 = src[1];
            half2v hp, mp;
            split2(v0.x, v0.y, hp, mp); h8[0]=hp.x; h8[1]=hp.y; m8[0]=mp.x; m8[1]=mp.y;
            split2(v0.z, v0.w, hp, mp); h8[2]=hp.x; h8[3]=hp.y; m8[2]=mp.x; m8[3]=mp.y;
            split2(v1.x, v1.y, hp, mp); h8[4]=hp.x; h8[5]=hp.y; m8[4]=mp.x; m8[5]=mp.y;
            split2(v1.z, v1.w, hp, mp); h8[6]=hp.x; h8[7]=hp.y; m8[6]=mp.x; m8[7]=mp.y;
        } else {
            #pragma unroll
            for (int j = 0; j < 8; ++j) { h8[j] = (_Float16)0.f; m8[j] = (_Float16)0.f; }
        }
        const int ci = chunkidx(slot, c16);
        P[0][ci] = h8;
        P[1][ci] = m8;
    }
    __syncthreads();

    float gv[4], bvv[4];
    #pragma unroll
    for (int nf = 0; nf < 4; ++nf) {
        gv[nf]  = gg[NGc + nf * 16 + l15];
        bvv[nf] = bbg[NGc + nf * 16 + l15];
    }

    f32x4 accH[5][4];
    f32x4 accM[5][4];

    // ================= conv1: 5 frags, single-buffered B =================
    {
        const int F1[5] = {-1, 15, 31, 47, 49};
        #pragma unroll
        for (int nf = 0; nf < 4; ++nf) {
            const float bz = b1g[NGc + nf * 16 + l15];
            const f32x4 b4 = {bz, bz, bz, bz};
            const f32x4 z4 = {0.f, 0.f, 0.f, 0.f};
            #pragma unroll
            for (int mf = 0; mf < 5; ++mf) { accH[mf][nf] = b4; accM[mf][nf] = z4; }
        }
        #pragma unroll 1
        for (int ks = 0; ks < KSTEPS; ++ks) {
            const int tap = ks >> 3, kk2 = ks & 7;
            half8v B[8];   // [plane*4 + nf]
            {
                const int fb = (tap * 8 + kk2) * 2;
                #pragma unroll
                for (int p = 0; p < 2; ++p)
                    #pragma unroll
                    for (int nf = 0; nf < 4; ++nf)
                        B[p * 4 + nf] = wsB[(size_t)((fb + p) * 16 + (wid * 4 + nf)) * 64 + lane];
            }
            #pragma unroll
            for (int mf = 0; mf < 5; ++mf) {
                const int slot = F1[mf] + l15 + tap + 1;   // (row-1+tap)+2
                const int ci = chunkidx(slot, kk2 * 4 + lg);
                const half8v Ah = P[0][ci];
                const half8v Am = P[1][ci];
                #pragma unroll
                for (int nf = 0; nf < 4; ++nf) {
                    accH[mf][nf] = __builtin_amdgcn_mfma_f32_16x16x32_f16(Ah, B[nf],     accH[mf][nf], 0, 0, 0);
                    accM[mf][nf] = __builtin_amdgcn_mfma_f32_16x16x32_f16(Ah, B[4 + nf], accM[mf][nf], 0, 0, 0);
                    accM[mf][nf] = __builtin_amdgcn_mfma_f32_16x16x32_f16(Am, B[nf],     accM[mf][nf], 0, 0, 0);
                }
            }
        }
        // combine + relu
        #pragma unroll
        for (int mf = 0; mf < 5; ++mf)
            #pragma unroll
            for (int nf = 0; nf < 4; ++nf) {
                f32x4 v;
                #pragma unroll
                for (int e = 0; e < 4; ++e)
                    v[e] = fmaxf(fmaf(accM[mf][nf][e], MINV, accH[mf][nf][e]), 0.f);
                accH[mf][nf] = v;
            }
        // LN single-pass stats (rows idx = row+1 in [0,65])
        #pragma unroll
        for (int mf = 0; mf < 5; ++mf)
            #pragma unroll
            for (int r = 0; r < 4; ++r) {
                float s = (accH[mf][0][r] + accH[mf][1][r]) + (accH[mf][2][r] + accH[mf][3][r]);
                float q = accH[mf][0][r] * accH[mf][0][r];
                q = fmaf(accH[mf][1][r], accH[mf][1][r], q);
                q = fmaf(accH[mf][2][r], accH[mf][2][r], q);
                q = fmaf(accH[mf][3][r], accH[mf][3][r], q);
                #pragma unroll
                for (int o = 1; o < 16; o <<= 1) {
                    s += __shfl_xor(s, o, 64);
                    q += __shfl_xor(q, o, 64);
                }
                if (l15 == 0) {
                    const int idx = F1[mf] + lg * 4 + r + 1;
                    sumS[wid][idx] = s;
                    sumQ[wid][idx] = q;
                }
            }
        __syncthreads();
        if (tid < 66) {
            const float S = (sumS[0][tid] + sumS[1][tid]) + (sumS[2][tid] + sumS[3][tid]);
            const float Q = (sumQ[0][tid] + sumQ[1][tid]) + (sumQ[2][tid] + sumQ[3][tid]);
            const float mu = S * (1.f / 256.f);
            const float var = fmaf(-mu, mu, Q * (1.f / 256.f));
            muS[tid] = mu;
            rsS[tid] = 1.0f / sqrtf(var + 1e-6f);
        }
        __syncthreads();
        // normalize + writeback x1 (h/m planes); rows outside [0,TT) forced 0
        _Float16* Ph = (_Float16*)&P[0][0];
        _Float16* Pm = (_Float16*)&P[1][0];
        #pragma unroll
        for (int mf = 0; mf < 5; ++mf)
            #pragma unroll
            for (int r = 0; r < 4; ++r) {
                const int row = F1[mf] + lg * 4 + r;
                const float mu = muS[row + 1];
                const float rs = rsS[row + 1];
                const bool valid = (base + row >= 0) && (base + row < TT);
                #pragma unroll
                for (int nf = 0; nf < 4; ++nf) {
                    float v = (accH[mf][nf][r] - mu) * rs * gv[nf] + bvv[nf];
                    if (!valid) v = 0.f;
                    const int col = NGc + nf * 16 + l15;
                    const int off = chunkidx(row + 2, col >> 3) * 8 + (col & 7);
                    const _Float16 h = (_Float16)v;   // RTNE
                    Ph[off] = h;
                    Pm[off] = (_Float16)fmaf((float)h, -MSCALE, v * MSCALE);
                }
            }
    }
    __syncthreads();

    // ================= conv2: 4 frags {0,16,32,48}, double-buffered B ====
    {
        #pragma unroll
        for (int nf = 0; nf < 4; ++nf) {
            const float bz = b2g[NGc + nf * 16 + l15];
            const f32x4 b4 = {bz, bz, bz, bz};
            const f32x4 z4 = {0.f, 0.f, 0.f, 0.f};
            #pragma unroll
            for (int mf = 0; mf < 4; ++mf) { accH[mf][nf] = b4; accM[mf][nf] = z4; }
        }
        half8v B0[8], B1[8];
        auto loadB = [&](half8v (&Bp)[8], int ks) {
            const int tap = ks >> 3, kk2 = ks & 7;
            const int fb = ((3 + tap) * 8 + kk2) * 2;    // cv=1
            #pragma unroll
            for (int p = 0; p < 2; ++p)
                #pragma unroll
                for (int nf = 0; nf < 4; ++nf)
                    Bp[p * 4 + nf] = wsB[(size_t)((fb + p) * 16 + (wid * 4 + nf)) * 64 + lane];
        };
        auto doK = [&](const half8v (&Bp)[8], int ks) {
            const int tap = ks >> 3, kk2 = ks & 7;
            #pragma unroll
            for (int mf = 0; mf < 4; ++mf) {
                const int slot = mf * 16 + l15 + tap + 1;
                const int ci = chunkidx(slot, kk2 * 4 + lg);
                const half8v Ah = P[0][ci];
                const half8v Am = P[1][ci];
                #pragma unroll
                for (int nf = 0; nf < 4; ++nf) {
                    accH[mf][nf] = __builtin_amdgcn_mfma_f32_16x16x32_f16(Ah, Bp[nf],     accH[mf][nf], 0, 0, 0);
                    accM[mf][nf] = __builtin_amdgcn_mfma_f32_16x16x32_f16(Ah, Bp[4 + nf], accM[mf][nf], 0, 0, 0);
                    accM[mf][nf] = __builtin_amdgcn_mfma_f32_16x16x32_f16(Am, Bp[nf],     accM[mf][nf], 0, 0, 0);
                }
            }
        };
        loadB(B0, 0);
        #pragma unroll 1
        for (int ks = 0; ks < KSTEPS; ks += 2) {
            loadB(B1, ks + 1);
            doK(B0, ks);
            if (ks + 2 < KSTEPS) loadB(B0, ks + 2);
            doK(B1, ks + 1);
        }
        // combine + relu
        #pragma unroll
        for (int mf = 0; mf < 4; ++mf)
            #pragma unroll
            for (int nf = 0; nf < 4; ++nf) {
                f32x4 v;
                #pragma unroll
                for (int e = 0; e < 4; ++e)
                    v[e] = fmaxf(fmaf(accM[mf][nf][e], MINV, accH[mf][nf][e]), 0.f);
                accH[mf][nf] = v;
            }
        // LN stats (rows 0..63)
        #pragma unroll
        for (int mf = 0; mf < 4; ++mf)
            #pragma unroll
            for (int r = 0; r < 4; ++r) {
                float s = (accH[mf][0][r] + accH[mf][1][r]) + (accH[mf][2][r] + accH[mf][3][r]);
                float q = accH[mf][0][r] * accH[mf][0][r];
                q = fmaf(accH[mf][1][r], accH[mf][1][r], q);
                q = fmaf(accH[mf][2][r], accH[mf][2][r], q);
                q = fmaf(accH[mf][3][r], accH[mf][3][r], q);
                #pragma unroll
                for (int o = 1; o < 16; o <<= 1) {
                    s += __shfl_xor(s, o, 64);
                    q += __shfl_xor(q, o, 64);
                }
                if (l15 == 0) {
                    const int idx = mf * 16 + lg * 4 + r;
                    sumS[wid][idx] = s;
                    sumQ[wid][idx] = q;
                }
            }
        __syncthreads();
        if (tid < 64) {
            const float S = (sumS[0][tid] + sumS[1][tid]) + (sumS[2][tid] + sumS[3][tid]);
            const float Q = (sumQ[0][tid] + sumQ[1][tid]) + (sumQ[2][tid] + sumQ[3][tid]);
            const float mu = S * (1.f / 256.f);
            const float var = fmaf(-mu, mu, Q * (1.f / 256.f));
            muS[tid] = mu;
            rsS[tid] = 1.0f / sqrtf(var + 1e-6f);
        }
        __syncthreads();
        // normalize in-regs, then dense partial dot
        float dv[4];
        #pragma unroll
        for (int nf = 0; nf < 4; ++nf) dv[nf] = dwg[NGc + nf * 16 + l15];
        #pragma unroll
        for (int mf = 0; mf < 4; ++mf)
            #pragma unroll
            for (int r = 0; r < 4; ++r) {
                const int row = mf * 16 + lg * 4 + r;
                const float mu = muS[row];
                const float rs = rsS[row];
                float p = 0.f;
                #pragma unroll
                for (int nf = 0; nf < 4; ++nf) {
                    const float v = (accH[mf][nf][r] - mu) * rs * gv[nf] + bvv[nf];
                    p = fmaf(v, dv[nf], p);
                }
                #pragma unroll
                for (int o = 1; o < 16; o <<= 1) p += __shfl_xor(p, o, 64);
                if (l15 == 0) sumS[wid][row] = p;
            }
        __syncthreads();
        if (tid < 64) {
            const float pd = (sumS[0][tid] + sumS[1][tid]) + (sumS[2][tid] + sumS[3][tid]) + dbg[0];
            const float dcl = fminf(fmaxf(pd, 0.0f), 75.0f);
            durG[b * TT + base + tid] = (int)rintf(dcl);   // RTNE matches jnp.round
        }
    }
}

// ---------------- cumsum + length-regulate gather (memory-bound) ----------
__global__ __launch_bounds__(256)
void va_gather(const float* __restrict__ enc, const int* __restrict__ durG,
               float* __restrict__ outg)
{
    __shared__ int cumS[TT];
    __shared__ int wtotS[2];
    const int b    = blockIdx.x;
    const int tid  = threadIdx.x;
    const int wid  = tid >> 6;
    const int lane = tid & 63;

    int sv = 0;
    if (tid < TT) {
        sv = durG[b * TT + tid];
        #pragma unroll
        for (int o = 1; o < 64; o <<= 1) {
            const int u = __shfl_up(sv, o, 64);
            if (lane >= o) sv += u;
        }
        if (lane == 63) wtotS[tid >> 6] = sv;
    }
    __syncthreads();
    if (tid < TT) {
        if (tid >= 64) sv += wtotS[0];
        cumS[tid] = sv;
    }
    __syncthreads();

    const int total = cumS[TT - 1];
    const f32x4* encB4 = reinterpret_cast<const f32x4*>(enc) + (size_t)b * (TT * 64);
    f32x4* outB4 = reinterpret_cast<f32x4*>(outg) + (size_t)b * (MAXLEN * 64);
    for (int pp = 0; pp < 20; ++pp) {
        const int p = wid * 20 + pp;     // 4 waves x 20 frames = 80
        int lo = 0, hi = TT;
        while (lo < hi) {                // uniform across the wave
            const int mid = (lo + hi) >> 1;
            if (cumS[mid] <= p) lo = mid + 1; else hi = mid;
        }
        f32x4 v = {0.f, 0.f, 0.f, 0.f};
        if (p < total) {
            const int src = (lo < TT) ? lo : (TT - 1);
            v = encB4[src * 64 + lane];
        }
        outB4[p * 64 + lane] = v;
    }
}

extern "C" void kernel_launch(void* const* d_in, const int* in_sizes, int n_in,
                              void* d_out, int out_size, void* d_ws, size_t ws_size,
                              hipStream_t stream) {
    const float* enc = (const float*)d_in[0];
    const float* w1  = (const float*)d_in[1];
    const float* b1  = (const float*)d_in[2];
    const float* w2  = (const float*)d_in[3];
    const float* b2  = (const float*)d_in[4];
    const float* gam = (const float*)d_in[5];
    const float* bet = (const float*)d_in[6];
    const float* dw  = (const float*)d_in[7];
    const float* db  = (const float*)d_in[8];
    float* out = (float*)d_out;
    half8v* wsB = (half8v*)d_ws;                          // 1,572,864 B
    int* durG = (int*)((char*)d_ws + 98304u * 16u);       // 1 MB of durations

    const int B = in_sizes[0] / (TT * CC);   // 2048
    hipLaunchKernelGGL(va_prep, dim3(384), dim3(256), 0, stream, w1, w2, wsB);
    hipLaunchKernelGGL(va_conv, dim3(B * 2), dim3(256), 0, stream,
                       enc, b1, b2, gam, bet, dw, db, wsB, durG);
    hipLaunchKernelGGL(va_gather, dim3(B), dim3(256), 0, stream, enc, durG, out);
}